// Round 10
// baseline (445.323 us; speedup 1.0000x reference)
//
#include <hip/hip_runtime.h>
#include <stdint.h>

#define NN 20000
#define NE 320000

typedef unsigned short us16;
typedef __attribute__((ext_vector_type(8))) short short8;
typedef __attribute__((ext_vector_type(4))) float f32x4;

union U4 { uint4 v; us16 s[8]; unsigned u[4]; };
union U2 { uint2 v; us16 s[4]; };

__device__ __forceinline__ float b2f(us16 u){ return __uint_as_float(((unsigned)u)<<16); }
__device__ __forceinline__ us16 f2b(float f){
  unsigned u = __float_as_uint(f);
  u += 0x7fffu + ((u>>16)&1u);
  return (us16)(u>>16);
}

// ---------------- merged misc: gat_w cvt + conv2 wprep + conv1 wprep + wl/wr + hist ----------------
__global__ __launch_bounds__(256) void k_misc(
    const float* __restrict__ gatw, us16* __restrict__ Wb,
    const float* __restrict__ w1, const float* __restrict__ w2, const float* __restrict__ w3,
    us16* __restrict__ Wt,
    const float* __restrict__ c1w1, const float* __restrict__ c1w2, const float* __restrict__ c1w3,
    const float* __restrict__ rp_w, us16* __restrict__ Wt1,
    const float* __restrict__ attnl, const float* __restrict__ attnr,
    float* __restrict__ wl, float* __restrict__ wr,
    const int* __restrict__ dst, int* __restrict__ counts)
{
  const int b = blockIdx.x, tid = threadIdx.x;
  if(b < 256){
    int i = b*256 + tid;
    float4 v = *(const float4*)(gatw + (size_t)i*4);
    U2 o;
    o.s[0]=f2b(v.x); o.s[1]=f2b(v.y); o.s[2]=f2b(v.z); o.s[3]=f2b(v.w);
    *(uint2*)(Wb + (size_t)i*4) = o.v;
  } else if(b < 400){
    int i = (b-256)*256 + tid;       // 36864: Wt[s][co3(96)][ci(128)]
    int s = i/12288, rem = i%12288;
    int co3 = rem>>7, ci = rem&127;
    const float* w = (co3<32) ? w1 : (co3<64) ? w2 : w3;
    Wt[i] = f2b(w[(co3&31)*384 + ci*3 + s]);
  } else if(b < 448){
    int i = (b-400)*256 + tid;       // 12288: Wt1[s][co3(128)][ci(32)]
    int s = i>>12, rem = i&4095;
    int co3 = rem>>5, ci = rem&31;
    float v;
    if(co3 < 96){
      const float* w = (co3<32) ? c1w1 : (co3<64) ? c1w2 : c1w3;
      v = w[(co3&31)*96 + ci*3 + s];
    } else {
      v = (s==1) ? rp_w[(co3-96)*32 + ci] : 0.f;
    }
    Wt1[i] = f2b(v);
  } else if(b < 456){
    // wl/wr[hd][k] = sum_f attn[hd][f] * W[hd*256+f][k]
    int bb = b-448;
    int sel = bb>>2, hd = bb&3, k = tid;
    const float* attn = sel ? attnr : attnl;
    float s = 0.f;
    #pragma unroll 8
    for(int f=0; f<256; f++)
      s = fmaf(attn[hd*256+f], gatw[(size_t)(hd*256+f)*256 + k], s);
    (sel ? wr : wl)[hd*256+k] = s;
  } else {
    int e = (b-456)*256 + tid;
    if(e < NE) atomicAdd(&counts[dst[e]], 1);
  }
}

// ---------------- conv1 (+residual k1) as MFMA GEMM, X read direct (fp32) ----------------
__global__ __launch_bounds__(256) void k_gemm1(
    const float* __restrict__ X, const us16* __restrict__ Wt1,
    const float* __restrict__ b1, const float* __restrict__ b2, const float* __restrict__ b3,
    const float* __restrict__ rp_b,
    us16* __restrict__ gc1, us16* __restrict__ resid,
    float* __restrict__ bn0_sum, float* __restrict__ bn0_sq)
{
  __shared__ float smemF[16896];
  us16* As = (us16*)smemF;                // [16][10][40]
  us16* Bs = As + 6400;                   // [3][128][40]
  float* Cs = smemF;                      // [128][132]
  __shared__ float redS[32], redQ[32];
  const int tid = threadIdx.x;
  if(tid<32){ redS[tid]=0.f; redQ[tid]=0.f; }
  const int node0 = blockIdx.x*16;
  const int lane = tid&63, wv = tid>>6;
  const int wm = wv&1, wn = wv>>1;
  const int mrow = lane&15, kg = (lane>>4)*8;
  for(int idx=tid; idx<1024; idx+=256){
    int n = idx>>6, rem = idx&63, slot = (rem>>5)*9, ci = rem&31;
    As[n*400 + slot*40 + ci] = 0;
  }
  #pragma unroll
  for(int i=0;i<4;i++){
    int idx = i*256 + tid;
    int n = idx>>6, rem = idx&63, ci = rem>>1, tq = rem&1;
    float4 xv = *(const float4*)(X + (size_t)(node0+n)*256 + ci*8 + tq*4);
    us16* p = &As[n*400 + (tq*4+1)*40 + ci];
    p[0]   = f2b(xv.x);
    p[40]  = f2b(xv.y);
    p[80]  = f2b(xv.z);
    p[120] = f2b(xv.w);
  }
  #pragma unroll
  for(int i=0;i<6;i++){
    int c = i*256 + tid;
    int s = c>>9, rem = c&511, co = rem>>2, cq = rem&3;
    *(uint4*)&Bs[s*5120 + co*40 + cq*8] = *(const uint4*)(Wt1 + s*4096 + co*32 + cq*8);
  }
  __syncthreads();
  f32x4 acc[4][4] = {};
  #pragma unroll
  for(int s=0; s<3; s++){
    short8 af[4], bfr[4];
    #pragma unroll
    for(int i=0;i<4;i++){
      int r = wm*64 + i*16 + mrow;
      af[i] = *(const short8*)&As[(r>>3)*400 + ((r&7)+s)*40 + kg];
    }
    #pragma unroll
    for(int j=0;j<4;j++)
      bfr[j] = *(const short8*)&Bs[s*5120 + (wn*64 + j*16 + mrow)*40 + kg];
    #pragma unroll
    for(int i=0;i<4;i++){
      #pragma unroll
      for(int j=0;j<4;j++)
        acc[i][j] = __builtin_amdgcn_mfma_f32_16x16x32_bf16(af[i], bfr[j], acc[i][j], 0, 0, 0);
    }
  }
  __syncthreads();
  #pragma unroll
  for(int i=0;i<4;i++){
    #pragma unroll
    for(int j=0;j<4;j++){
      #pragma unroll
      for(int r=0;r<4;r++)
        Cs[(wm*64 + i*16 + (lane>>4)*4 + r)*132 + wn*64 + j*16 + (lane&15)] = acc[i][j][r];
    }
  }
  __syncthreads();
  const int co = tid&31, rg = tid>>5;
  const float bb1=b1[co], bb2=b2[co], bb3=b3[co], bbr=rp_b[co];
  float s=0.f, q=0.f;
  #pragma unroll
  for(int half=0; half<2; half++){
    U4 ov, rv;
    #pragma unroll
    for(int t=0;t<8;t++){
      int r = rg*16 + half*8 + t;
      float c1 = Cs[r*132 + co]      + bb1;
      float c2 = Cs[r*132 + co + 32] + bb2;
      float c3 = Cs[r*132 + co + 64] + bb3;
      float rr = Cs[r*132 + co + 96] + bbr;
      float sg = 1.f/(1.f+__expf(-c2));
      float v = fmaf(c1, sg, c3);
      v = v>0.f ? v : 0.f;
      s += v; q += v*v;
      ov.s[t] = f2b(v);
      rv.s[t] = f2b(rr);
    }
    int node = node0 + rg*2 + half;
    *(uint4*)(gc1   + (size_t)node*256 + co*8) = ov.v;
    *(uint4*)(resid + (size_t)node*256 + co*8) = rv.v;
  }
  atomicAdd(&redS[co], s); atomicAdd(&redQ[co], q);
  __syncthreads();
  if(tid<32)      atomicAdd(&bn0_sum[tid], redS[tid]);
  else if(tid<64) atomicAdd(&bn0_sq[tid-32], redQ[tid-32]);
}

// ---------------- el/er from gc1 (bn0 folded) + CSR scan fused as block 5000 ----------------
__global__ __launch_bounds__(256) void k_eler2(const us16* __restrict__ gc1,
    const float* __restrict__ bn0_sum, const float* __restrict__ bn0_sq,
    const float* __restrict__ bn0g, const float* __restrict__ bn0b,
    const float* __restrict__ wl, const float* __restrict__ wr,
    float* __restrict__ el, float* __restrict__ er,
    const int* __restrict__ counts, int* __restrict__ offsets, int* __restrict__ cursor)
{
  const int tid = threadIdx.x;
  if(blockIdx.x < 5000){
    __shared__ float sa[32], sb[32];
    if(tid<32){
      float m = bn0_sum[tid]*(1.f/160000.f);
      float v = bn0_sq[tid]*(1.f/160000.f) - m*m;
      float a = bn0g[tid]*rsqrtf(v + 1e-5f);
      sa[tid] = a; sb[tid] = bn0b[tid] - m*a;
    }
    __syncthreads();
    const int wv = tid>>6, lane = tid&63;
    const int node = blockIdx.x*4 + wv;
    U2 g; g.v = *(const uint2*)(gc1 + (size_t)node*256 + lane*4);
    const float a = sa[lane>>1], b = sb[lane>>1];
    float xv[4];
    #pragma unroll
    for(int j=0;j<4;j++) xv[j] = fmaf(a, b2f(g.s[j]), b);
    float res[8];
    #pragma unroll
    for(int hd=0; hd<4; hd++){
      float4 lv = *(const float4*)(wl + hd*256 + lane*4);
      float4 rv = *(const float4*)(wr + hd*256 + lane*4);
      res[hd]   = xv[0]*lv.x + xv[1]*lv.y + xv[2]*lv.z + xv[3]*lv.w;
      res[4+hd] = xv[0]*rv.x + xv[1]*rv.y + xv[2]*rv.z + xv[3]*rv.w;
    }
    #pragma unroll
    for(int o=32;o;o>>=1){
      #pragma unroll
      for(int k=0;k<8;k++) res[k] += __shfl_xor(res[k], o, 64);
    }
    if(lane==0){
      #pragma unroll
      for(int hd=0;hd<4;hd++){ el[node*4+hd]=res[hd]; er[node*4+hd]=res[4+hd]; }
    }
  } else {
    // exclusive scan of counts -> offsets/cursor (256 threads x 79 items, two-pass)
    __shared__ int buf[256];
    const int base = tid*79;             // 256*79 = 20224 >= 20000
    int s = 0;
    for(int j=0;j<79;j++){
      int idx = base+j;
      if(idx<NN) s += counts[idx];
    }
    buf[tid] = s;
    __syncthreads();
    for(int off=1; off<256; off<<=1){
      int t = (tid>=off) ? buf[tid-off] : 0;
      __syncthreads();
      buf[tid] += t;
      __syncthreads();
    }
    int excl = buf[tid] - s;
    for(int j=0;j<79;j++){
      int idx = base+j;
      if(idx<NN){
        offsets[idx]=excl; cursor[idx]=excl;
        excl += counts[idx];
      }
    }
    if(tid==255) offsets[NN] = buf[255];
  }
}

// ---------------- scatter + edge scores ----------------
__global__ __launch_bounds__(256) void k_scatter(const int* __restrict__ src, const int* __restrict__ dst,
    int* __restrict__ cursor, int* __restrict__ esrc,
    const float* __restrict__ el, const float* __restrict__ er,
    float* __restrict__ ew)
{
  int e = blockIdx.x*256 + threadIdx.x;
  if(e < NE){
    int s = src[e], d = dst[e];
    int pos = atomicAdd(&cursor[d], 1);
    esrc[pos] = s;
    float4 lv = *(const float4*)(el + s*4);
    float4 rv = *(const float4*)(er + d*4);
    float4 sc;
    sc.x = lv.x+rv.x; sc.x = sc.x>0.f ? sc.x : 0.2f*sc.x;
    sc.y = lv.y+rv.y; sc.y = sc.y>0.f ? sc.y : 0.2f*sc.y;
    sc.z = lv.z+rv.z; sc.z = sc.z>0.f ? sc.z : 0.2f*sc.z;
    sc.w = lv.w+rv.w; sc.w = sc.w>0.f ? sc.w : 0.2f*sc.w;
    *(float4*)(ew + (size_t)pos*4) = sc;
  }
}

// ---------------- GAT aggregate in x-space: one wave per node, no LDS, no barriers ----------------
__global__ __launch_bounds__(256) void k_agg2(
    const int* __restrict__ offsets, const int* __restrict__ esrc,
    const float* __restrict__ ew, const us16* __restrict__ gc1,
    const float* __restrict__ bn0_sum, const float* __restrict__ bn0_sq,
    const float* __restrict__ bn0g, const float* __restrict__ bn0b,
    us16* __restrict__ Axg)
{
  const int tid = threadIdx.x;
  const int wv = tid>>6, lane = tid&63;
  const int node = blockIdx.x*4 + wv;
  const int ch = lane>>1;
  float mmn = bn0_sum[ch]*(1.f/160000.f);
  float vvn = bn0_sq[ch]*(1.f/160000.f) - mmn*mmn;
  float sa = bn0g[ch]*rsqrtf(vvn + 1e-5f);
  float sb = bn0b[ch] - mmn*sa;
  const int beg = offsets[node];
  const int deg = offsets[node+1] - beg;
  const int h = lane>>4, i0 = lane&15;
  float m = -3.0e38f;
  for(int i=i0; i<deg; i+=16) m = fmaxf(m, ew[(size_t)(beg+i)*4 + h]);
  m = fmaxf(m, __shfl_xor(m,1,64)); m = fmaxf(m, __shfl_xor(m,2,64));
  m = fmaxf(m, __shfl_xor(m,4,64)); m = fmaxf(m, __shfl_xor(m,8,64));
  float den = 0.f;
  for(int i=i0; i<deg; i+=16) den += __expf(ew[(size_t)(beg+i)*4 + h] - m);
  den += __shfl_xor(den,1,64); den += __shfl_xor(den,2,64);
  den += __shfl_xor(den,4,64); den += __shfl_xor(den,8,64);
  const float m0=__shfl(m,0,64),   m1=__shfl(m,16,64),  m2=__shfl(m,32,64),  m3=__shfl(m,48,64);
  const float d0=__shfl(den,0,64), d1=__shfl(den,16,64),d2=__shfl(den,32,64),d3=__shfl(den,48,64);
  const float v0=d0>0.f?1.f/d0:0.f, v1=d1>0.f?1.f/d1:0.f,
              v2=d2>0.f?1.f/d2:0.f, v3=d3>0.f?1.f/d3:0.f;
  float a0c[4]={},a1c[4]={},a2c[4]={},a3c[4]={};
  #pragma unroll 4
  for(int j=0; j<deg; j++){
    int pos = beg+j;
    float4 w4 = *(const float4*)(ew + (size_t)pos*4);
    int sN = esrc[pos];
    U2 hv; hv.v = *(const uint2*)(gc1 + (size_t)sN*256 + lane*4);
    float e0 = __expf(w4.x-m0)*v0;
    float e1 = __expf(w4.y-m1)*v1;
    float e2 = __expf(w4.z-m2)*v2;
    float e3 = __expf(w4.w-m3)*v3;
    #pragma unroll
    for(int kk=0;kk<4;kk++){
      float x = b2f(hv.s[kk]);
      a0c[kk] = fmaf(e0,x,a0c[kk]);
      a1c[kk] = fmaf(e1,x,a1c[kk]);
      a2c[kk] = fmaf(e2,x,a2c[kk]);
      a3c[kk] = fmaf(e3,x,a3c[kk]);
    }
  }
  const float sbi = sb * ((deg>0)?1.f:0.f);
  U2 o0,o1,o2,o3;
  #pragma unroll
  for(int kk=0;kk<4;kk++){
    o0.s[kk]=f2b(fmaf(sa,a0c[kk],sbi));
    o1.s[kk]=f2b(fmaf(sa,a1c[kk],sbi));
    o2.s[kk]=f2b(fmaf(sa,a2c[kk],sbi));
    o3.s[kk]=f2b(fmaf(sa,a3c[kk],sbi));
  }
  *(uint2*)(Axg + ((size_t)node)*256            + lane*4) = o0.v;
  *(uint2*)(Axg + ((size_t)NN + node)*256       + lane*4) = o1.v;
  *(uint2*)(Axg + ((size_t)2*NN + node)*256     + lane*4) = o2.v;
  *(uint2*)(Axg + ((size_t)3*NN + node)*256     + lane*4) = o3.v;
}

// ---------------- rst GEMM: full 256 cols per head per block + fused bn1 stats ----------------
__global__ __launch_bounds__(256) void k_gemm3(const us16* __restrict__ Axg, const us16* __restrict__ Wb,
    const float* __restrict__ gbias, us16* __restrict__ rst,
    float* __restrict__ bn1_sum, float* __restrict__ bn1_sq)
{
  __shared__ us16 As[128*72];   // 18432 B
  __shared__ us16 Bs[256*72];   // 36864 B
  const int tid = threadIdx.x;
  const int row0 = blockIdx.x*128;
  const int hd   = blockIdx.y;
  const us16* A = Axg + (size_t)hd*NN*256;
  const us16* B = Wb  + (size_t)hd*256*256;
  const int lane = tid&63, wv = tid>>6;
  const int wm = wv&1, wn = wv>>1;          // wn: 2 halves of 256 cols (128 each)
  const int mrow = lane&15, kg = (lane>>4)*8;
  f32x4 acc[4][8] = {};
  for(int k0=0; k0<256; k0+=64){
    #pragma unroll
    for(int i=0;i<4;i++){
      int chunk = i*256 + tid;
      int row = chunk>>3, cc = chunk&7;
      int g = row0 + row;
      uint4 av; av.x=0;av.y=0;av.z=0;av.w=0;
      if(g < NN) av = *(const uint4*)(A + (size_t)g*256 + k0 + cc*8);
      *(uint4*)&As[row*72 + cc*8] = av;
    }
    #pragma unroll
    for(int i=0;i<8;i++){
      int chunk = i*256 + tid;
      int row = chunk>>3, cc = chunk&7;
      *(uint4*)&Bs[row*72 + cc*8] = *(const uint4*)(B + (size_t)row*256 + k0 + cc*8);
    }
    __syncthreads();
    #pragma unroll
    for(int kk=0; kk<64; kk+=32){
      short8 af[4], bfr[8];
      #pragma unroll
      for(int i=0;i<4;i++) af[i]  = *(const short8*)&As[(wm*64 + i*16 + mrow)*72 + kk + kg];
      #pragma unroll
      for(int j=0;j<8;j++) bfr[j] = *(const short8*)&Bs[(wn*128 + j*16 + mrow)*72 + kk + kg];
      #pragma unroll
      for(int i=0;i<4;i++){
        #pragma unroll
        for(int j=0;j<8;j++)
          acc[i][j] = __builtin_amdgcn_mfma_f32_16x16x32_bf16(af[i], bfr[j], acc[i][j], 0, 0, 0);
      }
    }
    __syncthreads();
  }
  float gb[8];
  #pragma unroll
  for(int j=0;j<8;j++)
    gb[j] = gbias[hd*256 + wn*128 + j*16 + (lane&15)];
  float cs[8]={}, cq[8]={};
  #pragma unroll
  for(int i=0;i<4;i++){
    #pragma unroll
    for(int j=0;j<8;j++){
      #pragma unroll
      for(int r=0;r<4;r++){
        int g = row0 + wm*64 + i*16 + (lane>>4)*4 + r;
        if(g < NN){
          float v = acc[i][j][r] + gb[j];
          v = v>0.f ? v : 0.f;
          rst[(size_t)g*1024 + hd*256 + wn*128 + j*16 + (lane&15)] = f2b(v);
          cs[j] += v; cq[j] += v*v;
        }
      }
    }
  }
  #pragma unroll
  for(int j=0;j<8;j++){
    cs[j] += __shfl_xor(cs[j],16,64); cs[j] += __shfl_xor(cs[j],32,64);
    cq[j] += __shfl_xor(cq[j],16,64); cq[j] += __shfl_xor(cq[j],32,64);
  }
  if(lane < 16){
    #pragma unroll
    for(int j=0;j<8;j++){
      int col = hd*256 + wn*128 + j*16 + lane;
      atomicAdd(&bn1_sum[col], cs[j]);
      atomicAdd(&bn1_sq[col],  cq[j]);
    }
  }
}

// ---------------- conv2 as MFMA GEMM; rst direct, bn1 at staging ----------------
__global__ __launch_bounds__(256) void k_gemm2(
    const us16* __restrict__ rst, const us16* __restrict__ Wt,
    const float* __restrict__ bn1_sum, const float* __restrict__ bn1_sq,
    const float* __restrict__ bn1g, const float* __restrict__ bn1b,
    const float* __restrict__ b1, const float* __restrict__ b2, const float* __restrict__ b3,
    us16* __restrict__ y2, float* __restrict__ bn2_sum, float* __restrict__ bn2_sq)
{
  __shared__ float smemF[16384];
  float* s1a = smemF;
  float* s1b = smemF + 1024;
  us16* As = (us16*)(smemF + 2048);       // [16][10][136]
  us16* Bs = As + 21760;                  // [96][72]
  float* Cs = (float*)(smemF + 2048);     // [128][100]
  __shared__ float redS[32], redQ[32];
  const int tid = threadIdx.x;
  if(tid<32){ redS[tid]=0.f; redQ[tid]=0.f; }
  const int node0 = blockIdx.x*16;
  const int lane = tid&63, wv = tid>>6;
  const int wm = wv&1, wn = wv>>1;
  const int mrow = lane&15, kg = (lane>>4)*8;
  for(int f=tid; f<1024; f+=256){
    float m = bn1_sum[f]*(1.f/20000.f);
    float v = bn1_sq[f]*(1.f/20000.f) - m*m;
    float a = bn1g[f]*rsqrtf(v + 1e-5f);
    int l = (f&7)*128 + (f>>3);
    s1a[l] = a; s1b[l] = bn1b[f] - m*a;
  }
  for(int idx=tid; idx<4096; idx+=256){
    int n = idx>>8, rem = idx&255, slot = (rem>>7)*9, ci = rem&127;
    As[n*1360 + slot*136 + ci] = 0;
  }
  __syncthreads();
  #pragma unroll
  for(int i=0;i<8;i++){
    int idx = i*256 + tid;
    int n = idx>>7, ci = idx&127;
    U4 in; in.v = *(const uint4*)(rst + (size_t)(node0+n)*1024 + ci*8);
    us16* p = &As[n*1360 + 136 + ci];
    #pragma unroll
    for(int t=0;t<8;t++){
      float a = s1a[t*128+ci], b = s1b[t*128+ci];
      p[t*136] = f2b(fmaf(a, b2f(in.s[t]), b));
    }
  }
  f32x4 acc[4][3] = {};
  for(int rd=0; rd<6; rd++){
    const int s = rd>>1, kc = rd&1;
    __syncthreads();
    #pragma unroll
    for(int i=0;i<3;i++){
      int chunk = i*256 + tid;
      int brow = chunk>>3, cc = chunk&7;
      *(uint4*)&Bs[brow*72 + cc*8] =
        *(const uint4*)(Wt + s*12288 + brow*128 + kc*64 + cc*8);
    }
    __syncthreads();
    #pragma unroll
    for(int kk=0; kk<64; kk+=32){
      short8 af[4], bfr[3];
      #pragma unroll
      for(int i=0;i<4;i++){
        int r = wm*64 + i*16 + mrow;
        af[i] = *(const short8*)&As[(r>>3)*1360 + ((r&7)+s)*136 + kc*64 + kk + kg];
      }
      #pragma unroll
      for(int j=0;j<3;j++)
        bfr[j] = *(const short8*)&Bs[(wn*48 + j*16 + mrow)*72 + kk + kg];
      #pragma unroll
      for(int i=0;i<4;i++){
        #pragma unroll
        for(int j=0;j<3;j++)
          acc[i][j] = __builtin_amdgcn_mfma_f32_16x16x32_bf16(af[i], bfr[j], acc[i][j], 0, 0, 0);
      }
    }
  }
  __syncthreads();
  #pragma unroll
  for(int i=0;i<4;i++){
    #pragma unroll
    for(int j=0;j<3;j++){
      #pragma unroll
      for(int r=0;r<4;r++)
        Cs[(wm*64 + i*16 + (lane>>4)*4 + r)*100 + wn*48 + j*16 + (lane&15)] = acc[i][j][r];
    }
  }
  __syncthreads();
  const int co = tid&31, rg = tid>>5;
  const float bb1=b1[co], bb2=b2[co], bb3=b3[co];
  float s=0.f, q=0.f;
  #pragma unroll
  for(int half=0; half<2; half++){
    U4 ov;
    #pragma unroll
    for(int t=0;t<8;t++){
      int r = rg*16 + half*8 + t;
      float c1 = Cs[r*100 + co]      + bb1;
      float c2 = Cs[r*100 + co + 32] + bb2;
      float c3 = Cs[r*100 + co + 64] + bb3;
      float sg = 1.f/(1.f+__expf(-c2));
      float v = fmaf(c1, sg, c3);
      v = v>0.f ? v : 0.f;
      s += v; q += v*v;
      ov.s[t] = f2b(v);
    }
    int node = node0 + rg*2 + half;
    *(uint4*)(y2 + (size_t)node*256 + co*8) = ov.v;
  }
  atomicAdd(&redS[co], s); atomicAdd(&redQ[co], q);
  __syncthreads();
  if(tid<32)      atomicAdd(&bn2_sum[tid], redS[tid]);
  else if(tid<64) atomicAdd(&bn2_sq[tid-32], redQ[tid-32]);
}

// ---------------- final ----------------
__global__ __launch_bounds__(256) void k_final(const us16* __restrict__ y2,
    const float* __restrict__ bn2_sum, const float* __restrict__ bn2_sq,
    const float* __restrict__ bn2g, const float* __restrict__ bn2b,
    const us16* __restrict__ resid, float* __restrict__ out)
{
  __shared__ float fa[32], fb[32];
  const int tid = threadIdx.x;
  if(tid<32){
    float m = bn2_sum[tid]*(1.f/160000.f);
    float v = bn2_sq[tid]*(1.f/160000.f) - m*m;
    float a = bn2g[tid]*rsqrtf(v + 1e-5f);
    fa[tid] = a; fb[tid] = bn2b[tid] - m*a;
  }
  __syncthreads();
  size_t base = ((size_t)blockIdx.x*256 + tid)*8;
  int ch = (int)((base>>3)&31);
  float a = fa[ch], b = fb[ch];
  U4 yv, rv;
  yv.v = *(const uint4*)(y2+base);
  rv.v = *(const uint4*)(resid+base);
  float4 o0, o1;
  float vv[8];
  #pragma unroll
  for(int j=0;j<8;j++){
    float v = fmaf(a, b2f(yv.s[j]), b) + b2f(rv.s[j]);
    vv[j] = v>0.f ? v : 0.f;
  }
  o0.x=vv[0]; o0.y=vv[1]; o0.z=vv[2]; o0.w=vv[3];
  o1.x=vv[4]; o1.y=vv[5]; o1.z=vv[6]; o1.w=vv[7];
  *(float4*)(out+base)   = o0;
  *(float4*)(out+base+4) = o1;
}

extern "C" void kernel_launch(void* const* d_in, const int* in_sizes, int n_in,
                              void* d_out, int out_size, void* d_ws, size_t ws_size,
                              hipStream_t stream)
{
  const float* X    = (const float*)d_in[0];
  const int*  src   = (const int*)d_in[1];
  const int*  dst   = (const int*)d_in[2];
  const float* rp_w = (const float*)d_in[3];
  const float* rp_b = (const float*)d_in[4];
  const float* g1w1 = (const float*)d_in[5];
  const float* g1b1 = (const float*)d_in[6];
  const float* g1w2 = (const float*)d_in[7];
  const float* g1b2 = (const float*)d_in[8];
  const float* g1w3 = (const float*)d_in[9];
  const float* g1b3 = (const float*)d_in[10];
  const float* bn0g = (const float*)d_in[11];
  const float* bn0b = (const float*)d_in[12];
  const float* gatw = (const float*)d_in[13];
  const float* attnl= (const float*)d_in[14];
  const float* attnr= (const float*)d_in[15];
  const float* gbias= (const float*)d_in[16];
  const float* bn1g = (const float*)d_in[17];
  const float* bn1b = (const float*)d_in[18];
  const float* g2w1 = (const float*)d_in[19];
  const float* g2b1 = (const float*)d_in[20];
  const float* g2w2 = (const float*)d_in[21];
  const float* g2b2 = (const float*)d_in[22];
  const float* g2w3 = (const float*)d_in[23];
  const float* g2b3 = (const float*)d_in[24];
  const float* bn2g = (const float*)d_in[25];
  const float* bn2b = (const float*)d_in[26];
  float* out = (float*)d_out;
  (void)in_sizes; (void)n_in; (void)out_size; (void)ws_size;

  char* w = (char*)d_ws;
  float* bn0_sum = (float*)w;                 // 32
  float* bn0_sq  = bn0_sum + 32;              // 32
  float* bn1_sum = bn0_sum + 64;              // 1024
  float* bn1_sq  = bn1_sum + 1024;            // 1024
  float* bn2_sum = bn1_sq  + 1024;            // 32
  float* bn2_sq  = bn2_sum + 32;              // 32
  int*   counts  = (int*)(bn2_sq + 32);       // 20000
  size_t zeroBytes = (size_t)((char*)(counts + NN) - w);   // ~88.7 KB
  int*   offsets = counts + NN;               // 20004
  int*   cursor  = offsets + 20004;           // 20000
  int*   esrc    = cursor + NN;               // 320000
  float* el      = (float*)(esrc + NE);       // 80000
  float* er      = el + NN*4;                 // 80000
  float* ew      = er + NN*4;                 // 1,280,000
  float* wl      = ew + (size_t)NE*4;         // 1024
  float* wr      = wl + 1024;                 // 1024
  us16*  wb      = (us16*)(wr + 1024);        // 262144
  us16*  resid   = wb + 262144;               // 5,120,000
  us16*  gc1     = resid + 5120000;           // 5,120,000 (raw gated conv1)
  us16*  Axg     = gc1   + 5120000;           // 20,480,000  [hd][node][256]
  us16*  rst     = Axg   + 20480000;          // 20,480,000
  us16*  Wt      = rst   + 20480000;          // 36,864
  us16*  Wt1     = Wt    + 36864;             // 12,288
  us16*  y2      = gc1;                       // alias: gc1 dead after k_agg2

  hipMemsetAsync(d_ws, 0, zeroBytes, stream);
  k_misc<<<1706, 256, 0, stream>>>(gatw, wb, g2w1, g2w2, g2w3, Wt,
                                   g1w1, g1w2, g1w3, rp_w, Wt1,
                                   attnl, attnr, wl, wr, dst, counts);
  k_gemm1<<<1250, 256, 0, stream>>>(X, Wt1, g1b1, g1b2, g1b3, rp_b,
                                    gc1, resid, bn0_sum, bn0_sq);
  k_eler2<<<5001, 256, 0, stream>>>(gc1, bn0_sum, bn0_sq, bn0g, bn0b, wl, wr, el, er,
                                    counts, offsets, cursor);
  k_scatter<<<1250, 256, 0, stream>>>(src, dst, cursor, esrc, el, er, ew);
  k_agg2<<<5000, 256, 0, stream>>>(offsets, esrc, ew, gc1, bn0_sum, bn0_sq, bn0g, bn0b, Axg);
  k_gemm3<<<dim3(157, 4), 256, 0, stream>>>(Axg, wb, gbias, rst, bn1_sum, bn1_sq);
  k_gemm2<<<1250, 256, 0, stream>>>(rst, Wt, bn1_sum, bn1_sq, bn1g, bn1b,
                                    g2b1, g2b2, g2b3, y2, bn2_sum, bn2_sq);
  k_final<<<2500, 256, 0, stream>>>(y2, bn2_sum, bn2_sq, bn2g, bn2b, resid, out);
}

// Round 11
// 401.920 us; speedup vs baseline: 1.1080x; 1.1080x over previous
//
#include <hip/hip_runtime.h>
#include <stdint.h>

#define NN 20000
#define NE 320000

typedef unsigned short us16;
typedef __attribute__((ext_vector_type(8))) short short8;
typedef __attribute__((ext_vector_type(4))) float f32x4;

union U4 { uint4 v; us16 s[8]; unsigned u[4]; };
union U2 { uint2 v; us16 s[4]; };

__device__ __forceinline__ float b2f(us16 u){ return __uint_as_float(((unsigned)u)<<16); }
__device__ __forceinline__ us16 f2b(float f){
  unsigned u = __float_as_uint(f);
  u += 0x7fffu + ((u>>16)&1u);
  return (us16)(u>>16);
}

// ---------------- merged misc: gat_w cvt + conv2 wprep + conv1 wprep + wl/wr + hist ----------------
__global__ __launch_bounds__(256) void k_misc(
    const float* __restrict__ gatw, us16* __restrict__ Wb,
    const float* __restrict__ w1, const float* __restrict__ w2, const float* __restrict__ w3,
    us16* __restrict__ Wt,
    const float* __restrict__ c1w1, const float* __restrict__ c1w2, const float* __restrict__ c1w3,
    const float* __restrict__ rp_w, us16* __restrict__ Wt1,
    const float* __restrict__ attnl, const float* __restrict__ attnr,
    float* __restrict__ wl, float* __restrict__ wr,
    const int* __restrict__ dst, int* __restrict__ counts)
{
  const int b = blockIdx.x, tid = threadIdx.x;
  if(b < 256){
    int i = b*256 + tid;
    float4 v = *(const float4*)(gatw + (size_t)i*4);
    U2 o;
    o.s[0]=f2b(v.x); o.s[1]=f2b(v.y); o.s[2]=f2b(v.z); o.s[3]=f2b(v.w);
    *(uint2*)(Wb + (size_t)i*4) = o.v;
  } else if(b < 400){
    int i = (b-256)*256 + tid;       // 36864: Wt[s][co3(96)][ci(128)]
    int s = i/12288, rem = i%12288;
    int co3 = rem>>7, ci = rem&127;
    const float* w = (co3<32) ? w1 : (co3<64) ? w2 : w3;
    Wt[i] = f2b(w[(co3&31)*384 + ci*3 + s]);
  } else if(b < 448){
    int i = (b-400)*256 + tid;       // 12288: Wt1[s][co3(128)][ci(32)]
    int s = i>>12, rem = i&4095;
    int co3 = rem>>5, ci = rem&31;
    float v;
    if(co3 < 96){
      const float* w = (co3<32) ? c1w1 : (co3<64) ? c1w2 : c1w3;
      v = w[(co3&31)*96 + ci*3 + s];
    } else {
      v = (s==1) ? rp_w[(co3-96)*32 + ci] : 0.f;
    }
    Wt1[i] = f2b(v);
  } else if(b < 480){
    // wl/wr[hd][k] += sum over f-quarter of attn[hd][f] * W[hd*256+f][k]
    int bb = b-448;                   // 0..31
    int sel = bb>>4, hd = (bb>>2)&3, fq = bb&3;
    const float* attn = sel ? attnr : attnl;
    int k = tid;
    float s = 0.f;
    int f0 = fq*64;
    #pragma unroll 8
    for(int f=f0; f<f0+64; f++)
      s = fmaf(attn[hd*256+f], gatw[(size_t)(hd*256+f)*256 + k], s);
    atomicAdd(&((sel ? wr : wl)[hd*256+k]), s);
  } else {
    int e = (b-480)*256 + tid;
    if(e < NE) atomicAdd(&counts[dst[e]], 1);
  }
}

// ---------------- conv1 (+residual k1) as MFMA GEMM, X read direct (fp32) ----------------
__global__ __launch_bounds__(256) void k_gemm1(
    const float* __restrict__ X, const us16* __restrict__ Wt1,
    const float* __restrict__ b1, const float* __restrict__ b2, const float* __restrict__ b3,
    const float* __restrict__ rp_b,
    us16* __restrict__ gc1, us16* __restrict__ resid,
    float* __restrict__ bn0_sum, float* __restrict__ bn0_sq)
{
  __shared__ float smemF[16896];
  us16* As = (us16*)smemF;                // [16][10][40]
  us16* Bs = As + 6400;                   // [3][128][40]
  float* Cs = smemF;                      // [128][132]
  __shared__ float redS[32], redQ[32];
  const int tid = threadIdx.x;
  if(tid<32){ redS[tid]=0.f; redQ[tid]=0.f; }
  const int node0 = blockIdx.x*16;
  const int lane = tid&63, wv = tid>>6;
  const int wm = wv&1, wn = wv>>1;
  const int mrow = lane&15, kg = (lane>>4)*8;
  for(int idx=tid; idx<1024; idx+=256){
    int n = idx>>6, rem = idx&63, slot = (rem>>5)*9, ci = rem&31;
    As[n*400 + slot*40 + ci] = 0;
  }
  #pragma unroll
  for(int i=0;i<4;i++){
    int idx = i*256 + tid;
    int n = idx>>6, rem = idx&63, ci = rem>>1, tq = rem&1;
    float4 xv = *(const float4*)(X + (size_t)(node0+n)*256 + ci*8 + tq*4);
    us16* p = &As[n*400 + (tq*4+1)*40 + ci];
    p[0]   = f2b(xv.x);
    p[40]  = f2b(xv.y);
    p[80]  = f2b(xv.z);
    p[120] = f2b(xv.w);
  }
  #pragma unroll
  for(int i=0;i<6;i++){
    int c = i*256 + tid;
    int s = c>>9, rem = c&511, co = rem>>2, cq = rem&3;
    *(uint4*)&Bs[s*5120 + co*40 + cq*8] = *(const uint4*)(Wt1 + s*4096 + co*32 + cq*8);
  }
  __syncthreads();
  f32x4 acc[4][4] = {};
  #pragma unroll
  for(int s=0; s<3; s++){
    short8 af[4], bfr[4];
    #pragma unroll
    for(int i=0;i<4;i++){
      int r = wm*64 + i*16 + mrow;
      af[i] = *(const short8*)&As[(r>>3)*400 + ((r&7)+s)*40 + kg];
    }
    #pragma unroll
    for(int j=0;j<4;j++)
      bfr[j] = *(const short8*)&Bs[s*5120 + (wn*64 + j*16 + mrow)*40 + kg];
    #pragma unroll
    for(int i=0;i<4;i++){
      #pragma unroll
      for(int j=0;j<4;j++)
        acc[i][j] = __builtin_amdgcn_mfma_f32_16x16x32_bf16(af[i], bfr[j], acc[i][j], 0, 0, 0);
    }
  }
  __syncthreads();
  #pragma unroll
  for(int i=0;i<4;i++){
    #pragma unroll
    for(int j=0;j<4;j++){
      #pragma unroll
      for(int r=0;r<4;r++)
        Cs[(wm*64 + i*16 + (lane>>4)*4 + r)*132 + wn*64 + j*16 + (lane&15)] = acc[i][j][r];
    }
  }
  __syncthreads();
  const int co = tid&31, rg = tid>>5;
  const float bb1=b1[co], bb2=b2[co], bb3=b3[co], bbr=rp_b[co];
  float s=0.f, q=0.f;
  #pragma unroll
  for(int half=0; half<2; half++){
    U4 ov, rv;
    #pragma unroll
    for(int t=0;t<8;t++){
      int r = rg*16 + half*8 + t;
      float c1 = Cs[r*132 + co]      + bb1;
      float c2 = Cs[r*132 + co + 32] + bb2;
      float c3 = Cs[r*132 + co + 64] + bb3;
      float rr = Cs[r*132 + co + 96] + bbr;
      float sg = 1.f/(1.f+__expf(-c2));
      float v = fmaf(c1, sg, c3);
      v = v>0.f ? v : 0.f;
      s += v; q += v*v;
      ov.s[t] = f2b(v);
      rv.s[t] = f2b(rr);
    }
    int node = node0 + rg*2 + half;
    *(uint4*)(gc1   + (size_t)node*256 + co*8) = ov.v;
    *(uint4*)(resid + (size_t)node*256 + co*8) = rv.v;
  }
  atomicAdd(&redS[co], s); atomicAdd(&redQ[co], q);
  __syncthreads();
  if(tid<32)      atomicAdd(&bn0_sum[tid], redS[tid]);
  else if(tid<64) atomicAdd(&bn0_sq[tid-32], redQ[tid-32]);
}

// ---------------- el/er from gc1 (bn0 folded) + CSR scan fused as block 5000 ----------------
__global__ __launch_bounds__(256) void k_eler2(const us16* __restrict__ gc1,
    const float* __restrict__ bn0_sum, const float* __restrict__ bn0_sq,
    const float* __restrict__ bn0g, const float* __restrict__ bn0b,
    const float* __restrict__ wl, const float* __restrict__ wr,
    float* __restrict__ el, float* __restrict__ er,
    const int* __restrict__ counts, int* __restrict__ offsets, int* __restrict__ cursor)
{
  const int tid = threadIdx.x;
  if(blockIdx.x < 5000){
    __shared__ float sa[32], sb[32];
    if(tid<32){
      float m = bn0_sum[tid]*(1.f/160000.f);
      float v = bn0_sq[tid]*(1.f/160000.f) - m*m;
      float a = bn0g[tid]*rsqrtf(v + 1e-5f);
      sa[tid] = a; sb[tid] = bn0b[tid] - m*a;
    }
    __syncthreads();
    const int wv = tid>>6, lane = tid&63;
    const int node = blockIdx.x*4 + wv;
    U2 g; g.v = *(const uint2*)(gc1 + (size_t)node*256 + lane*4);
    const float a = sa[lane>>1], b = sb[lane>>1];
    float xv[4];
    #pragma unroll
    for(int j=0;j<4;j++) xv[j] = fmaf(a, b2f(g.s[j]), b);
    float res[8];
    #pragma unroll
    for(int hd=0; hd<4; hd++){
      float4 lv = *(const float4*)(wl + hd*256 + lane*4);
      float4 rv = *(const float4*)(wr + hd*256 + lane*4);
      res[hd]   = xv[0]*lv.x + xv[1]*lv.y + xv[2]*lv.z + xv[3]*lv.w;
      res[4+hd] = xv[0]*rv.x + xv[1]*rv.y + xv[2]*rv.z + xv[3]*rv.w;
    }
    #pragma unroll
    for(int o=32;o;o>>=1){
      #pragma unroll
      for(int k=0;k<8;k++) res[k] += __shfl_xor(res[k], o, 64);
    }
    if(lane==0){
      #pragma unroll
      for(int hd=0;hd<4;hd++){ el[node*4+hd]=res[hd]; er[node*4+hd]=res[4+hd]; }
    }
  } else {
    __shared__ int buf[256];
    const int base = tid*79;             // 256*79 = 20224 >= 20000
    int s = 0;
    for(int j=0;j<79;j++){
      int idx = base+j;
      if(idx<NN) s += counts[idx];
    }
    buf[tid] = s;
    __syncthreads();
    for(int off=1; off<256; off<<=1){
      int t = (tid>=off) ? buf[tid-off] : 0;
      __syncthreads();
      buf[tid] += t;
      __syncthreads();
    }
    int excl = buf[tid] - s;
    for(int j=0;j<79;j++){
      int idx = base+j;
      if(idx<NN){
        offsets[idx]=excl; cursor[idx]=excl;
        excl += counts[idx];
      }
    }
    if(tid==255) offsets[NN] = buf[255];
  }
}

// ---------------- scatter + edge scores ----------------
__global__ __launch_bounds__(256) void k_scatter(const int* __restrict__ src, const int* __restrict__ dst,
    int* __restrict__ cursor, int* __restrict__ esrc,
    const float* __restrict__ el, const float* __restrict__ er,
    float* __restrict__ ew)
{
  int e = blockIdx.x*256 + threadIdx.x;
  if(e < NE){
    int s = src[e], d = dst[e];
    int pos = atomicAdd(&cursor[d], 1);
    esrc[pos] = s;
    float4 lv = *(const float4*)(el + s*4);
    float4 rv = *(const float4*)(er + d*4);
    float4 sc;
    sc.x = lv.x+rv.x; sc.x = sc.x>0.f ? sc.x : 0.2f*sc.x;
    sc.y = lv.y+rv.y; sc.y = sc.y>0.f ? sc.y : 0.2f*sc.y;
    sc.z = lv.z+rv.z; sc.z = sc.z>0.f ? sc.z : 0.2f*sc.z;
    sc.w = lv.w+rv.w; sc.w = sc.w>0.f ? sc.w : 0.2f*sc.w;
    *(float4*)(ew + (size_t)pos*4) = sc;
  }
}

// ---------------- GAT aggregate in x-space: one wave per node, no LDS, no barriers ----------------
__global__ __launch_bounds__(256) void k_agg2(
    const int* __restrict__ offsets, const int* __restrict__ esrc,
    const float* __restrict__ ew, const us16* __restrict__ gc1,
    const float* __restrict__ bn0_sum, const float* __restrict__ bn0_sq,
    const float* __restrict__ bn0g, const float* __restrict__ bn0b,
    us16* __restrict__ Axg)
{
  const int tid = threadIdx.x;
  const int wv = tid>>6, lane = tid&63;
  const int node = blockIdx.x*4 + wv;
  const int ch = lane>>1;
  float mmn = bn0_sum[ch]*(1.f/160000.f);
  float vvn = bn0_sq[ch]*(1.f/160000.f) - mmn*mmn;
  float sa = bn0g[ch]*rsqrtf(vvn + 1e-5f);
  float sb = bn0b[ch] - mmn*sa;
  const int beg = offsets[node];
  const int deg = offsets[node+1] - beg;
  const int h = lane>>4, i0 = lane&15;
  float m = -3.0e38f;
  for(int i=i0; i<deg; i+=16) m = fmaxf(m, ew[(size_t)(beg+i)*4 + h]);
  m = fmaxf(m, __shfl_xor(m,1,64)); m = fmaxf(m, __shfl_xor(m,2,64));
  m = fmaxf(m, __shfl_xor(m,4,64)); m = fmaxf(m, __shfl_xor(m,8,64));
  float den = 0.f;
  for(int i=i0; i<deg; i+=16) den += __expf(ew[(size_t)(beg+i)*4 + h] - m);
  den += __shfl_xor(den,1,64); den += __shfl_xor(den,2,64);
  den += __shfl_xor(den,4,64); den += __shfl_xor(den,8,64);
  const float m0=__shfl(m,0,64),   m1=__shfl(m,16,64),  m2=__shfl(m,32,64),  m3=__shfl(m,48,64);
  const float d0=__shfl(den,0,64), d1=__shfl(den,16,64),d2=__shfl(den,32,64),d3=__shfl(den,48,64);
  const float v0=d0>0.f?1.f/d0:0.f, v1=d1>0.f?1.f/d1:0.f,
              v2=d2>0.f?1.f/d2:0.f, v3=d3>0.f?1.f/d3:0.f;
  float a0c[4]={},a1c[4]={},a2c[4]={},a3c[4]={};
  #pragma unroll 4
  for(int j=0; j<deg; j++){
    int pos = beg+j;
    float4 w4 = *(const float4*)(ew + (size_t)pos*4);
    int sN = esrc[pos];
    U2 hv; hv.v = *(const uint2*)(gc1 + (size_t)sN*256 + lane*4);
    float e0 = __expf(w4.x-m0)*v0;
    float e1 = __expf(w4.y-m1)*v1;
    float e2 = __expf(w4.z-m2)*v2;
    float e3 = __expf(w4.w-m3)*v3;
    #pragma unroll
    for(int kk=0;kk<4;kk++){
      float x = b2f(hv.s[kk]);
      a0c[kk] = fmaf(e0,x,a0c[kk]);
      a1c[kk] = fmaf(e1,x,a1c[kk]);
      a2c[kk] = fmaf(e2,x,a2c[kk]);
      a3c[kk] = fmaf(e3,x,a3c[kk]);
    }
  }
  const float sbi = sb * ((deg>0)?1.f:0.f);
  U2 o0,o1,o2,o3;
  #pragma unroll
  for(int kk=0;kk<4;kk++){
    o0.s[kk]=f2b(fmaf(sa,a0c[kk],sbi));
    o1.s[kk]=f2b(fmaf(sa,a1c[kk],sbi));
    o2.s[kk]=f2b(fmaf(sa,a2c[kk],sbi));
    o3.s[kk]=f2b(fmaf(sa,a3c[kk],sbi));
  }
  *(uint2*)(Axg + ((size_t)node)*256            + lane*4) = o0.v;
  *(uint2*)(Axg + ((size_t)NN + node)*256       + lane*4) = o1.v;
  *(uint2*)(Axg + ((size_t)2*NN + node)*256     + lane*4) = o2.v;
  *(uint2*)(Axg + ((size_t)3*NN + node)*256     + lane*4) = o3.v;
}

// ---------------- rst GEMM: BK=32, small LDS (20.5KB) for high occupancy + fused bn1 stats ----------------
__global__ __launch_bounds__(256) void k_gemm3(const us16* __restrict__ Axg, const us16* __restrict__ Wb,
    const float* __restrict__ gbias, us16* __restrict__ rst,
    float* __restrict__ bn1_sum, float* __restrict__ bn1_sq)
{
  __shared__ us16 As[128*40];   // 10240 B
  __shared__ us16 Bs[128*40];   // 10240 B
  const int tid = threadIdx.x;
  const int row0 = blockIdx.x*128;
  const int cb   = blockIdx.y*128;
  const int hd   = blockIdx.z;
  const us16* A = Axg + (size_t)hd*NN*256;
  const us16* B = Wb  + (size_t)(hd*256 + cb)*256;
  const int lane = tid&63, wv = tid>>6;
  const int wm = wv&1, wn = wv>>1;
  const int mrow = lane&15, kg = (lane>>4)*8;
  f32x4 acc[4][4] = {};
  for(int k0=0; k0<256; k0+=32){
    #pragma unroll
    for(int i=0;i<2;i++){
      int chunk = i*256 + tid;          // 512 chunks = 128 rows x 4 cc
      int row = chunk>>2, cc = chunk&3;
      int g = row0 + row;
      uint4 av; av.x=0;av.y=0;av.z=0;av.w=0;
      if(g < NN) av = *(const uint4*)(A + (size_t)g*256 + k0 + cc*8);
      *(uint4*)&As[row*40 + cc*8] = av;
      *(uint4*)&Bs[row*40 + cc*8] = *(const uint4*)(B + (size_t)row*256 + k0 + cc*8);
    }
    __syncthreads();
    short8 af[4], bfr[4];
    #pragma unroll
    for(int i=0;i<4;i++) af[i]  = *(const short8*)&As[(wm*64 + i*16 + mrow)*40 + kg];
    #pragma unroll
    for(int j=0;j<4;j++) bfr[j] = *(const short8*)&Bs[(wn*64 + j*16 + mrow)*40 + kg];
    #pragma unroll
    for(int i=0;i<4;i++){
      #pragma unroll
      for(int j=0;j<4;j++)
        acc[i][j] = __builtin_amdgcn_mfma_f32_16x16x32_bf16(af[i], bfr[j], acc[i][j], 0, 0, 0);
    }
    __syncthreads();
  }
  float gb[4];
  #pragma unroll
  for(int j=0;j<4;j++)
    gb[j] = gbias[hd*256 + cb + wn*64 + j*16 + (lane&15)];
  float cs[4]={}, cq[4]={};
  #pragma unroll
  for(int i=0;i<4;i++){
    #pragma unroll
    for(int j=0;j<4;j++){
      #pragma unroll
      for(int r=0;r<4;r++){
        int g = row0 + wm*64 + i*16 + (lane>>4)*4 + r;
        if(g < NN){
          float v = acc[i][j][r] + gb[j];
          v = v>0.f ? v : 0.f;
          rst[(size_t)g*1024 + hd*256 + cb + wn*64 + j*16 + (lane&15)] = f2b(v);
          cs[j] += v; cq[j] += v*v;
        }
      }
    }
  }
  #pragma unroll
  for(int j=0;j<4;j++){
    cs[j] += __shfl_xor(cs[j],16,64); cs[j] += __shfl_xor(cs[j],32,64);
    cq[j] += __shfl_xor(cq[j],16,64); cq[j] += __shfl_xor(cq[j],32,64);
  }
  if(lane < 16){
    #pragma unroll
    for(int j=0;j<4;j++){
      int col = hd*256 + cb + wn*64 + j*16 + lane;
      atomicAdd(&bn1_sum[col], cs[j]);
      atomicAdd(&bn1_sq[col],  cq[j]);
    }
  }
}

// ---------------- conv2 as MFMA GEMM; rst direct, bn1 at staging ----------------
__global__ __launch_bounds__(256) void k_gemm2(
    const us16* __restrict__ rst, const us16* __restrict__ Wt,
    const float* __restrict__ bn1_sum, const float* __restrict__ bn1_sq,
    const float* __restrict__ bn1g, const float* __restrict__ bn1b,
    const float* __restrict__ b1, const float* __restrict__ b2, const float* __restrict__ b3,
    us16* __restrict__ y2, float* __restrict__ bn2_sum, float* __restrict__ bn2_sq)
{
  __shared__ float smemF[16384];
  float* s1a = smemF;
  float* s1b = smemF + 1024;
  us16* As = (us16*)(smemF + 2048);       // [16][10][136]
  us16* Bs = As + 21760;                  // [96][72]
  float* Cs = (float*)(smemF + 2048);     // [128][100]
  __shared__ float redS[32], redQ[32];
  const int tid = threadIdx.x;
  if(tid<32){ redS[tid]=0.f; redQ[tid]=0.f; }
  const int node0 = blockIdx.x*16;
  const int lane = tid&63, wv = tid>>6;
  const int wm = wv&1, wn = wv>>1;
  const int mrow = lane&15, kg = (lane>>4)*8;
  for(int f=tid; f<1024; f+=256){
    float m = bn1_sum[f]*(1.f/20000.f);
    float v = bn1_sq[f]*(1.f/20000.f) - m*m;
    float a = bn1g[f]*rsqrtf(v + 1e-5f);
    int l = (f&7)*128 + (f>>3);
    s1a[l] = a; s1b[l] = bn1b[f] - m*a;
  }
  for(int idx=tid; idx<4096; idx+=256){
    int n = idx>>8, rem = idx&255, slot = (rem>>7)*9, ci = rem&127;
    As[n*1360 + slot*136 + ci] = 0;
  }
  __syncthreads();
  #pragma unroll
  for(int i=0;i<8;i++){
    int idx = i*256 + tid;
    int n = idx>>7, ci = idx&127;
    U4 in; in.v = *(const uint4*)(rst + (size_t)(node0+n)*1024 + ci*8);
    us16* p = &As[n*1360 + 136 + ci];
    #pragma unroll
    for(int t=0;t<8;t++){
      float a = s1a[t*128+ci], b = s1b[t*128+ci];
      p[t*136] = f2b(fmaf(a, b2f(in.s[t]), b));
    }
  }
  f32x4 acc[4][3] = {};
  for(int rd=0; rd<6; rd++){
    const int s = rd>>1, kc = rd&1;
    __syncthreads();
    #pragma unroll
    for(int i=0;i<3;i++){
      int chunk = i*256 + tid;
      int brow = chunk>>3, cc = chunk&7;
      *(uint4*)&Bs[brow*72 + cc*8] =
        *(const uint4*)(Wt + s*12288 + brow*128 + kc*64 + cc*8);
    }
    __syncthreads();
    #pragma unroll
    for(int kk=0; kk<64; kk+=32){
      short8 af[4], bfr[3];
      #pragma unroll
      for(int i=0;i<4;i++){
        int r = wm*64 + i*16 + mrow;
        af[i] = *(const short8*)&As[(r>>3)*1360 + ((r&7)+s)*136 + kc*64 + kk + kg];
      }
      #pragma unroll
      for(int j=0;j<3;j++)
        bfr[j] = *(const short8*)&Bs[(wn*48 + j*16 + mrow)*72 + kk + kg];
      #pragma unroll
      for(int i=0;i<4;i++){
        #pragma unroll
        for(int j=0;j<3;j++)
          acc[i][j] = __builtin_amdgcn_mfma_f32_16x16x32_bf16(af[i], bfr[j], acc[i][j], 0, 0, 0);
      }
    }
  }
  __syncthreads();
  #pragma unroll
  for(int i=0;i<4;i++){
    #pragma unroll
    for(int j=0;j<3;j++){
      #pragma unroll
      for(int r=0;r<4;r++)
        Cs[(wm*64 + i*16 + (lane>>4)*4 + r)*100 + wn*48 + j*16 + (lane&15)] = acc[i][j][r];
    }
  }
  __syncthreads();
  const int co = tid&31, rg = tid>>5;
  const float bb1=b1[co], bb2=b2[co], bb3=b3[co];
  float s=0.f, q=0.f;
  #pragma unroll
  for(int half=0; half<2; half++){
    U4 ov;
    #pragma unroll
    for(int t=0;t<8;t++){
      int r = rg*16 + half*8 + t;
      float c1 = Cs[r*100 + co]      + bb1;
      float c2 = Cs[r*100 + co + 32] + bb2;
      float c3 = Cs[r*100 + co + 64] + bb3;
      float sg = 1.f/(1.f+__expf(-c2));
      float v = fmaf(c1, sg, c3);
      v = v>0.f ? v : 0.f;
      s += v; q += v*v;
      ov.s[t] = f2b(v);
    }
    int node = node0 + rg*2 + half;
    *(uint4*)(y2 + (size_t)node*256 + co*8) = ov.v;
  }
  atomicAdd(&redS[co], s); atomicAdd(&redQ[co], q);
  __syncthreads();
  if(tid<32)      atomicAdd(&bn2_sum[tid], redS[tid]);
  else if(tid<64) atomicAdd(&bn2_sq[tid-32], redQ[tid-32]);
}

// ---------------- final ----------------
__global__ __launch_bounds__(256) void k_final(const us16* __restrict__ y2,
    const float* __restrict__ bn2_sum, const float* __restrict__ bn2_sq,
    const float* __restrict__ bn2g, const float* __restrict__ bn2b,
    const us16* __restrict__ resid, float* __restrict__ out)
{
  __shared__ float fa[32], fb[32];
  const int tid = threadIdx.x;
  if(tid<32){
    float m = bn2_sum[tid]*(1.f/160000.f);
    float v = bn2_sq[tid]*(1.f/160000.f) - m*m;
    float a = bn2g[tid]*rsqrtf(v + 1e-5f);
    fa[tid] = a; fb[tid] = bn2b[tid] - m*a;
  }
  __syncthreads();
  size_t base = ((size_t)blockIdx.x*256 + tid)*8;
  int ch = (int)((base>>3)&31);
  float a = fa[ch], b = fb[ch];
  U4 yv, rv;
  yv.v = *(const uint4*)(y2+base);
  rv.v = *(const uint4*)(resid+base);
  float4 o0, o1;
  float vv[8];
  #pragma unroll
  for(int j=0;j<8;j++){
    float v = fmaf(a, b2f(yv.s[j]), b) + b2f(rv.s[j]);
    vv[j] = v>0.f ? v : 0.f;
  }
  o0.x=vv[0]; o0.y=vv[1]; o0.z=vv[2]; o0.w=vv[3];
  o1.x=vv[4]; o1.y=vv[5]; o1.z=vv[6]; o1.w=vv[7];
  *(float4*)(out+base)   = o0;
  *(float4*)(out+base+4) = o1;
}

extern "C" void kernel_launch(void* const* d_in, const int* in_sizes, int n_in,
                              void* d_out, int out_size, void* d_ws, size_t ws_size,
                              hipStream_t stream)
{
  const float* X    = (const float*)d_in[0];
  const int*  src   = (const int*)d_in[1];
  const int*  dst   = (const int*)d_in[2];
  const float* rp_w = (const float*)d_in[3];
  const float* rp_b = (const float*)d_in[4];
  const float* g1w1 = (const float*)d_in[5];
  const float* g1b1 = (const float*)d_in[6];
  const float* g1w2 = (const float*)d_in[7];
  const float* g1b2 = (const float*)d_in[8];
  const float* g1w3 = (const float*)d_in[9];
  const float* g1b3 = (const float*)d_in[10];
  const float* bn0g = (const float*)d_in[11];
  const float* bn0b = (const float*)d_in[12];
  const float* gatw = (const float*)d_in[13];
  const float* attnl= (const float*)d_in[14];
  const float* attnr= (const float*)d_in[15];
  const float* gbias= (const float*)d_in[16];
  const float* bn1g = (const float*)d_in[17];
  const float* bn1b = (const float*)d_in[18];
  const float* g2w1 = (const float*)d_in[19];
  const float* g2b1 = (const float*)d_in[20];
  const float* g2w2 = (const float*)d_in[21];
  const float* g2b2 = (const float*)d_in[22];
  const float* g2w3 = (const float*)d_in[23];
  const float* g2b3 = (const float*)d_in[24];
  const float* bn2g = (const float*)d_in[25];
  const float* bn2b = (const float*)d_in[26];
  float* out = (float*)d_out;
  (void)in_sizes; (void)n_in; (void)out_size; (void)ws_size;

  char* w = (char*)d_ws;
  float* bn0_sum = (float*)w;                 // 32
  float* bn0_sq  = bn0_sum + 32;              // 32
  float* bn1_sum = bn0_sum + 64;              // 1024
  float* bn1_sq  = bn1_sum + 1024;            // 1024
  float* bn2_sum = bn1_sq  + 1024;            // 32
  float* bn2_sq  = bn2_sum + 32;              // 32
  float* wl      = bn2_sq + 32;               // 1024 (zeroed: accumulated atomically)
  float* wr      = wl + 1024;                 // 1024
  int*   counts  = (int*)(wr + 1024);         // 20000
  size_t zeroBytes = (size_t)((char*)(counts + NN) - w);   // ~96.9 KB
  int*   offsets = counts + NN;               // 20004
  int*   cursor  = offsets + 20004;           // 20000
  int*   esrc    = cursor + NN;               // 320000
  float* el      = (float*)(esrc + NE);       // 80000
  float* er      = el + NN*4;                 // 80000
  float* ew      = er + NN*4;                 // 1,280,000
  us16*  wb      = (us16*)(ew + (size_t)NE*4);// 262144
  us16*  resid   = wb + 262144;               // 5,120,000
  us16*  gc1     = resid + 5120000;           // 5,120,000 (raw gated conv1)
  us16*  Axg     = gc1   + 5120000;           // 20,480,000  [hd][node][256]
  us16*  rst     = Axg   + 20480000;          // 20,480,000
  us16*  Wt      = rst   + 20480000;          // 36,864
  us16*  Wt1     = Wt    + 36864;             // 12,288
  us16*  y2      = gc1;                       // alias: gc1 dead after k_agg2

  hipMemsetAsync(d_ws, 0, zeroBytes, stream);
  k_misc<<<1730, 256, 0, stream>>>(gatw, wb, g2w1, g2w2, g2w3, Wt,
                                   g1w1, g1w2, g1w3, rp_w, Wt1,
                                   attnl, attnr, wl, wr, dst, counts);
  k_gemm1<<<1250, 256, 0, stream>>>(X, Wt1, g1b1, g1b2, g1b3, rp_b,
                                    gc1, resid, bn0_sum, bn0_sq);
  k_eler2<<<5001, 256, 0, stream>>>(gc1, bn0_sum, bn0_sq, bn0g, bn0b, wl, wr, el, er,
                                    counts, offsets, cursor);
  k_scatter<<<1250, 256, 0, stream>>>(src, dst, cursor, esrc, el, er, ew);
  k_agg2<<<5000, 256, 0, stream>>>(offsets, esrc, ew, gc1, bn0_sum, bn0_sq, bn0g, bn0b, Axg);
  k_gemm3<<<dim3(157, 2, 4), 256, 0, stream>>>(Axg, wb, gbias, rst, bn1_sum, bn1_sq);
  k_gemm2<<<1250, 256, 0, stream>>>(rst, Wt, bn1_sum, bn1_sq, bn1g, bn1b,
                                    g2b1, g2b2, g2b3, y2, bn2_sum, bn2_sq);
  k_final<<<2500, 256, 0, stream>>>(y2, bn2_sum, bn2_sq, bn2g, bn2b, resid, out);
}

// Round 12
// 381.632 us; speedup vs baseline: 1.1669x; 1.0532x over previous
//
#include <hip/hip_runtime.h>
#include <stdint.h>

#define NN 20000
#define NE 320000

typedef unsigned short us16;
typedef __attribute__((ext_vector_type(8))) short short8;
typedef __attribute__((ext_vector_type(4))) float f32x4;

union U4 { uint4 v; us16 s[8]; unsigned u[4]; };
union U2 { uint2 v; us16 s[4]; };

__device__ __forceinline__ float b2f(us16 u){ return __uint_as_float(((unsigned)u)<<16); }
__device__ __forceinline__ us16 f2b(float f){
  unsigned u = __float_as_uint(f);
  u += 0x7fffu + ((u>>16)&1u);
  return (us16)(u>>16);
}

// ---------------- merged misc: gat_w cvt + conv2 wprep + conv1 wprep + wl/wr + hist ----------------
__global__ __launch_bounds__(256) void k_misc(
    const float* __restrict__ gatw, us16* __restrict__ Wb,
    const float* __restrict__ w1, const float* __restrict__ w2, const float* __restrict__ w3,
    us16* __restrict__ Wt,
    const float* __restrict__ c1w1, const float* __restrict__ c1w2, const float* __restrict__ c1w3,
    const float* __restrict__ rp_w, us16* __restrict__ Wt1,
    const float* __restrict__ attnl, const float* __restrict__ attnr,
    float* __restrict__ wl, float* __restrict__ wr,
    const int* __restrict__ dst, int* __restrict__ counts)
{
  const int b = blockIdx.x, tid = threadIdx.x;
  if(b < 256){
    int i = b*256 + tid;
    float4 v = *(const float4*)(gatw + (size_t)i*4);
    U2 o;
    o.s[0]=f2b(v.x); o.s[1]=f2b(v.y); o.s[2]=f2b(v.z); o.s[3]=f2b(v.w);
    *(uint2*)(Wb + (size_t)i*4) = o.v;
  } else if(b < 400){
    int i = (b-256)*256 + tid;       // 36864: Wt[s][co3(96)][ci(128)]
    int s = i/12288, rem = i%12288;
    int co3 = rem>>7, ci = rem&127;
    const float* w = (co3<32) ? w1 : (co3<64) ? w2 : w3;
    Wt[i] = f2b(w[(co3&31)*384 + ci*3 + s]);
  } else if(b < 448){
    int i = (b-400)*256 + tid;       // 12288: Wt1[s][co3(128)][ci(32)]
    int s = i>>12, rem = i&4095;
    int co3 = rem>>5, ci = rem&31;
    float v;
    if(co3 < 96){
      const float* w = (co3<32) ? c1w1 : (co3<64) ? c1w2 : c1w3;
      v = w[(co3&31)*96 + ci*3 + s];
    } else {
      v = (s==1) ? rp_w[(co3-96)*32 + ci] : 0.f;
    }
    Wt1[i] = f2b(v);
  } else if(b < 480){
    int bb = b-448;                   // 0..31
    int sel = bb>>4, hd = (bb>>2)&3, fq = bb&3;
    const float* attn = sel ? attnr : attnl;
    int k = tid;
    float s = 0.f;
    int f0 = fq*64;
    #pragma unroll 8
    for(int f=f0; f<f0+64; f++)
      s = fmaf(attn[hd*256+f], gatw[(size_t)(hd*256+f)*256 + k], s);
    atomicAdd(&((sel ? wr : wl)[hd*256+k]), s);
  } else {
    int e = (b-480)*256 + tid;
    if(e < NE) atomicAdd(&counts[dst[e]], 1);
  }
}

// ---------------- conv1 (+residual k1) as MFMA GEMM + CSR scan as tail block ----------------
__global__ __launch_bounds__(256) void k_gemm1(
    const float* __restrict__ X, const us16* __restrict__ Wt1,
    const float* __restrict__ b1, const float* __restrict__ b2, const float* __restrict__ b3,
    const float* __restrict__ rp_b,
    us16* __restrict__ gc1, us16* __restrict__ resid,
    float* __restrict__ bn0_sum, float* __restrict__ bn0_sq,
    const int* __restrict__ counts, int* __restrict__ offsets, int* __restrict__ cursor)
{
  __shared__ float smemF[16896];
  __shared__ float redS[32], redQ[32];
  const int tid = threadIdx.x;
  if(blockIdx.x < 1250){
    us16* As = (us16*)smemF;                // [16][10][40]
    us16* Bs = As + 6400;                   // [3][128][40]
    float* Cs = smemF;                      // [128][132]
    if(tid<32){ redS[tid]=0.f; redQ[tid]=0.f; }
    const int node0 = blockIdx.x*16;
    const int lane = tid&63, wv = tid>>6;
    const int wm = wv&1, wn = wv>>1;
    const int mrow = lane&15, kg = (lane>>4)*8;
    for(int idx=tid; idx<1024; idx+=256){
      int n = idx>>6, rem = idx&63, slot = (rem>>5)*9, ci = rem&31;
      As[n*400 + slot*40 + ci] = 0;
    }
    #pragma unroll
    for(int i=0;i<4;i++){
      int idx = i*256 + tid;
      int n = idx>>6, rem = idx&63, ci = rem>>1, tq = rem&1;
      float4 xv = *(const float4*)(X + (size_t)(node0+n)*256 + ci*8 + tq*4);
      us16* p = &As[n*400 + (tq*4+1)*40 + ci];
      p[0]   = f2b(xv.x);
      p[40]  = f2b(xv.y);
      p[80]  = f2b(xv.z);
      p[120] = f2b(xv.w);
    }
    #pragma unroll
    for(int i=0;i<6;i++){
      int c = i*256 + tid;
      int s = c>>9, rem = c&511, co = rem>>2, cq = rem&3;
      *(uint4*)&Bs[s*5120 + co*40 + cq*8] = *(const uint4*)(Wt1 + s*4096 + co*32 + cq*8);
    }
    __syncthreads();
    f32x4 acc[4][4] = {};
    #pragma unroll
    for(int s=0; s<3; s++){
      short8 af[4], bfr[4];
      #pragma unroll
      for(int i=0;i<4;i++){
        int r = wm*64 + i*16 + mrow;
        af[i] = *(const short8*)&As[(r>>3)*400 + ((r&7)+s)*40 + kg];
      }
      #pragma unroll
      for(int j=0;j<4;j++)
        bfr[j] = *(const short8*)&Bs[s*5120 + (wn*64 + j*16 + mrow)*40 + kg];
      #pragma unroll
      for(int i=0;i<4;i++){
        #pragma unroll
        for(int j=0;j<4;j++)
          acc[i][j] = __builtin_amdgcn_mfma_f32_16x16x32_bf16(af[i], bfr[j], acc[i][j], 0, 0, 0);
      }
    }
    __syncthreads();
    #pragma unroll
    for(int i=0;i<4;i++){
      #pragma unroll
      for(int j=0;j<4;j++){
        #pragma unroll
        for(int r=0;r<4;r++)
          Cs[(wm*64 + i*16 + (lane>>4)*4 + r)*132 + wn*64 + j*16 + (lane&15)] = acc[i][j][r];
      }
    }
    __syncthreads();
    const int co = tid&31, rg = tid>>5;
    const float bb1=b1[co], bb2=b2[co], bb3=b3[co], bbr=rp_b[co];
    float s=0.f, q=0.f;
    #pragma unroll
    for(int half=0; half<2; half++){
      U4 ov, rv;
      #pragma unroll
      for(int t=0;t<8;t++){
        int r = rg*16 + half*8 + t;
        float c1 = Cs[r*132 + co]      + bb1;
        float c2 = Cs[r*132 + co + 32] + bb2;
        float c3 = Cs[r*132 + co + 64] + bb3;
        float rr = Cs[r*132 + co + 96] + bbr;
        float sg = 1.f/(1.f+__expf(-c2));
        float v = fmaf(c1, sg, c3);
        v = v>0.f ? v : 0.f;
        s += v; q += v*v;
        ov.s[t] = f2b(v);
        rv.s[t] = f2b(rr);
      }
      int node = node0 + rg*2 + half;
      *(uint4*)(gc1   + (size_t)node*256 + co*8) = ov.v;
      *(uint4*)(resid + (size_t)node*256 + co*8) = rv.v;
    }
    atomicAdd(&redS[co], s); atomicAdd(&redQ[co], q);
    __syncthreads();
    if(tid<32)      atomicAdd(&bn0_sum[tid], redS[tid]);
    else if(tid<64) atomicAdd(&bn0_sq[tid-32], redQ[tid-32]);
  } else {
    // ---- CSR exclusive scan, LDS-resident counts (coalesced, latency-free chains) ----
    us16* cnt  = (us16*)smemF;             // 20224 us16 = 40448 B
    int*  wsum = (int*)(smemF + 12800);    // 256 ints (byte 51200+)
    for(int r=0;r<79;r++){
      int idx = r*256 + tid;               // coalesced, independent
      cnt[idx] = (idx<NN) ? (us16)counts[idx] : (us16)0;
    }
    __syncthreads();
    const int base = tid*79;
    int s = 0;
    for(int j=0;j<79;j++) s += cnt[base+j];
    wsum[tid] = s;
    __syncthreads();
    for(int off=1; off<256; off<<=1){
      int t = (tid>=off) ? wsum[tid-off] : 0;
      __syncthreads();
      wsum[tid] += t;
      __syncthreads();
    }
    int excl = wsum[tid] - s;
    for(int j=0;j<79;j++){
      int idx = base+j;
      if(idx<NN){
        offsets[idx]=excl; cursor[idx]=excl;
        excl += cnt[idx];
      }
    }
    if(tid==255) offsets[NN] = wsum[255];
  }
}

// ---------------- el/er from gc1 (bn0 folded): wave per node ----------------
__global__ __launch_bounds__(256) void k_eler2(const us16* __restrict__ gc1,
    const float* __restrict__ bn0_sum, const float* __restrict__ bn0_sq,
    const float* __restrict__ bn0g, const float* __restrict__ bn0b,
    const float* __restrict__ wl, const float* __restrict__ wr,
    float* __restrict__ el, float* __restrict__ er)
{
  __shared__ float sa[32], sb[32];
  const int tid = threadIdx.x;
  if(tid<32){
    float m = bn0_sum[tid]*(1.f/160000.f);
    float v = bn0_sq[tid]*(1.f/160000.f) - m*m;
    float a = bn0g[tid]*rsqrtf(v + 1e-5f);
    sa[tid] = a; sb[tid] = bn0b[tid] - m*a;
  }
  __syncthreads();
  const int wv = tid>>6, lane = tid&63;
  const int node = blockIdx.x*4 + wv;
  U2 g; g.v = *(const uint2*)(gc1 + (size_t)node*256 + lane*4);
  const float a = sa[lane>>1], b = sb[lane>>1];
  float xv[4];
  #pragma unroll
  for(int j=0;j<4;j++) xv[j] = fmaf(a, b2f(g.s[j]), b);
  float res[8];
  #pragma unroll
  for(int hd=0; hd<4; hd++){
    float4 lv = *(const float4*)(wl + hd*256 + lane*4);
    float4 rv = *(const float4*)(wr + hd*256 + lane*4);
    res[hd]   = xv[0]*lv.x + xv[1]*lv.y + xv[2]*lv.z + xv[3]*lv.w;
    res[4+hd] = xv[0]*rv.x + xv[1]*rv.y + xv[2]*rv.z + xv[3]*rv.w;
  }
  #pragma unroll
  for(int o=32;o;o>>=1){
    #pragma unroll
    for(int k=0;k<8;k++) res[k] += __shfl_xor(res[k], o, 64);
  }
  if(lane==0){
    #pragma unroll
    for(int hd=0;hd<4;hd++){ el[node*4+hd]=res[hd]; er[node*4+hd]=res[4+hd]; }
  }
}

// ---------------- scatter + edge scores ----------------
__global__ __launch_bounds__(256) void k_scatter(const int* __restrict__ src, const int* __restrict__ dst,
    int* __restrict__ cursor, int* __restrict__ esrc,
    const float* __restrict__ el, const float* __restrict__ er,
    float* __restrict__ ew)
{
  int e = blockIdx.x*256 + threadIdx.x;
  if(e < NE){
    int s = src[e], d = dst[e];
    int pos = atomicAdd(&cursor[d], 1);
    esrc[pos] = s;
    float4 lv = *(const float4*)(el + s*4);
    float4 rv = *(const float4*)(er + d*4);
    float4 sc;
    sc.x = lv.x+rv.x; sc.x = sc.x>0.f ? sc.x : 0.2f*sc.x;
    sc.y = lv.y+rv.y; sc.y = sc.y>0.f ? sc.y : 0.2f*sc.y;
    sc.z = lv.z+rv.z; sc.z = sc.z>0.f ? sc.z : 0.2f*sc.z;
    sc.w = lv.w+rv.w; sc.w = sc.w>0.f ? sc.w : 0.2f*sc.w;
    *(float4*)(ew + (size_t)pos*4) = sc;
  }
}

// ---------------- GAT aggregate in x-space: one wave per node, no LDS, no barriers ----------------
__global__ __launch_bounds__(256) void k_agg2(
    const int* __restrict__ offsets, const int* __restrict__ esrc,
    const float* __restrict__ ew, const us16* __restrict__ gc1,
    const float* __restrict__ bn0_sum, const float* __restrict__ bn0_sq,
    const float* __restrict__ bn0g, const float* __restrict__ bn0b,
    us16* __restrict__ Axg)
{
  const int tid = threadIdx.x;
  const int wv = tid>>6, lane = tid&63;
  const int node = blockIdx.x*4 + wv;
  const int ch = lane>>1;
  float mmn = bn0_sum[ch]*(1.f/160000.f);
  float vvn = bn0_sq[ch]*(1.f/160000.f) - mmn*mmn;
  float sa = bn0g[ch]*rsqrtf(vvn + 1e-5f);
  float sb = bn0b[ch] - mmn*sa;
  const int beg = offsets[node];
  const int deg = offsets[node+1] - beg;
  const int h = lane>>4, i0 = lane&15;
  float m = -3.0e38f;
  for(int i=i0; i<deg; i+=16) m = fmaxf(m, ew[(size_t)(beg+i)*4 + h]);
  m = fmaxf(m, __shfl_xor(m,1,64)); m = fmaxf(m, __shfl_xor(m,2,64));
  m = fmaxf(m, __shfl_xor(m,4,64)); m = fmaxf(m, __shfl_xor(m,8,64));
  float den = 0.f;
  for(int i=i0; i<deg; i+=16) den += __expf(ew[(size_t)(beg+i)*4 + h] - m);
  den += __shfl_xor(den,1,64); den += __shfl_xor(den,2,64);
  den += __shfl_xor(den,4,64); den += __shfl_xor(den,8,64);
  const float m0=__shfl(m,0,64),   m1=__shfl(m,16,64),  m2=__shfl(m,32,64),  m3=__shfl(m,48,64);
  const float d0=__shfl(den,0,64), d1=__shfl(den,16,64),d2=__shfl(den,32,64),d3=__shfl(den,48,64);
  const float v0=d0>0.f?1.f/d0:0.f, v1=d1>0.f?1.f/d1:0.f,
              v2=d2>0.f?1.f/d2:0.f, v3=d3>0.f?1.f/d3:0.f;
  float a0c[4]={},a1c[4]={},a2c[4]={},a3c[4]={};
  #pragma unroll 4
  for(int j=0; j<deg; j++){
    int pos = beg+j;
    float4 w4 = *(const float4*)(ew + (size_t)pos*4);
    int sN = esrc[pos];
    U2 hv; hv.v = *(const uint2*)(gc1 + (size_t)sN*256 + lane*4);
    float e0 = __expf(w4.x-m0)*v0;
    float e1 = __expf(w4.y-m1)*v1;
    float e2 = __expf(w4.z-m2)*v2;
    float e3 = __expf(w4.w-m3)*v3;
    #pragma unroll
    for(int kk=0;kk<4;kk++){
      float x = b2f(hv.s[kk]);
      a0c[kk] = fmaf(e0,x,a0c[kk]);
      a1c[kk] = fmaf(e1,x,a1c[kk]);
      a2c[kk] = fmaf(e2,x,a2c[kk]);
      a3c[kk] = fmaf(e3,x,a3c[kk]);
    }
  }
  const float sbi = sb * ((deg>0)?1.f:0.f);
  U2 o0,o1,o2,o3;
  #pragma unroll
  for(int kk=0;kk<4;kk++){
    o0.s[kk]=f2b(fmaf(sa,a0c[kk],sbi));
    o1.s[kk]=f2b(fmaf(sa,a1c[kk],sbi));
    o2.s[kk]=f2b(fmaf(sa,a2c[kk],sbi));
    o3.s[kk]=f2b(fmaf(sa,a3c[kk],sbi));
  }
  *(uint2*)(Axg + ((size_t)node)*256            + lane*4) = o0.v;
  *(uint2*)(Axg + ((size_t)NN + node)*256       + lane*4) = o1.v;
  *(uint2*)(Axg + ((size_t)2*NN + node)*256     + lane*4) = o2.v;
  *(uint2*)(Axg + ((size_t)3*NN + node)*256     + lane*4) = o3.v;
}

// ---------------- rst GEMM: BK=32, small LDS + fused bn1 stats ----------------
__global__ __launch_bounds__(256) void k_gemm3(const us16* __restrict__ Axg, const us16* __restrict__ Wb,
    const float* __restrict__ gbias, us16* __restrict__ rst,
    float* __restrict__ bn1_sum, float* __restrict__ bn1_sq)
{
  __shared__ us16 As[128*40];   // 10240 B
  __shared__ us16 Bs[128*40];   // 10240 B
  const int tid = threadIdx.x;
  const int row0 = blockIdx.x*128;
  const int cb   = blockIdx.y*128;
  const int hd   = blockIdx.z;
  const us16* A = Axg + (size_t)hd*NN*256;
  const us16* B = Wb  + (size_t)(hd*256 + cb)*256;
  const int lane = tid&63, wv = tid>>6;
  const int wm = wv&1, wn = wv>>1;
  const int mrow = lane&15, kg = (lane>>4)*8;
  f32x4 acc[4][4] = {};
  for(int k0=0; k0<256; k0+=32){
    #pragma unroll
    for(int i=0;i<2;i++){
      int chunk = i*256 + tid;
      int row = chunk>>2, cc = chunk&3;
      int g = row0 + row;
      uint4 av; av.x=0;av.y=0;av.z=0;av.w=0;
      if(g < NN) av = *(const uint4*)(A + (size_t)g*256 + k0 + cc*8);
      *(uint4*)&As[row*40 + cc*8] = av;
      *(uint4*)&Bs[row*40 + cc*8] = *(const uint4*)(B + (size_t)row*256 + k0 + cc*8);
    }
    __syncthreads();
    short8 af[4], bfr[4];
    #pragma unroll
    for(int i=0;i<4;i++) af[i]  = *(const short8*)&As[(wm*64 + i*16 + mrow)*40 + kg];
    #pragma unroll
    for(int j=0;j<4;j++) bfr[j] = *(const short8*)&Bs[(wn*64 + j*16 + mrow)*40 + kg];
    #pragma unroll
    for(int i=0;i<4;i++){
      #pragma unroll
      for(int j=0;j<4;j++)
        acc[i][j] = __builtin_amdgcn_mfma_f32_16x16x32_bf16(af[i], bfr[j], acc[i][j], 0, 0, 0);
    }
    __syncthreads();
  }
  float gb[4];
  #pragma unroll
  for(int j=0;j<4;j++)
    gb[j] = gbias[hd*256 + cb + wn*64 + j*16 + (lane&15)];
  float cs[4]={}, cq[4]={};
  #pragma unroll
  for(int i=0;i<4;i++){
    #pragma unroll
    for(int j=0;j<4;j++){
      #pragma unroll
      for(int r=0;r<4;r++){
        int g = row0 + wm*64 + i*16 + (lane>>4)*4 + r;
        if(g < NN){
          float v = acc[i][j][r] + gb[j];
          v = v>0.f ? v : 0.f;
          rst[(size_t)g*1024 + hd*256 + cb + wn*64 + j*16 + (lane&15)] = f2b(v);
          cs[j] += v; cq[j] += v*v;
        }
      }
    }
  }
  #pragma unroll
  for(int j=0;j<4;j++){
    cs[j] += __shfl_xor(cs[j],16,64); cs[j] += __shfl_xor(cs[j],32,64);
    cq[j] += __shfl_xor(cq[j],16,64); cq[j] += __shfl_xor(cq[j],32,64);
  }
  if(lane < 16){
    #pragma unroll
    for(int j=0;j<4;j++){
      int col = hd*256 + cb + wn*64 + j*16 + lane;
      atomicAdd(&bn1_sum[col], cs[j]);
      atomicAdd(&bn1_sq[col],  cq[j]);
    }
  }
}

// ---------------- conv2 as MFMA GEMM; kc-major A-halves, 51.2KB LDS (3 blocks/CU) ----------------
__global__ __launch_bounds__(256) void k_gemm2(
    const us16* __restrict__ rst, const us16* __restrict__ Wt,
    const float* __restrict__ bn1_sum, const float* __restrict__ bn1_sq,
    const float* __restrict__ bn1g, const float* __restrict__ bn1b,
    const float* __restrict__ b1, const float* __restrict__ b2, const float* __restrict__ b3,
    us16* __restrict__ y2, float* __restrict__ bn2_sum, float* __restrict__ bn2_sq)
{
  __shared__ float smemF[12800];          // 51200 B
  float* s1a = smemF;                     // [t][ci] 1024
  float* s1b = smemF + 1024;              // 1024
  us16* As = (us16*)(smemF + 2048);       // [16][10][72] = 11520 (one kc half)
  us16* Bs = As + 11520;                  // [96][72] = 6912
  float* Cs = smemF;                      // [128][100] epilogue overlay
  __shared__ float redS[32], redQ[32];
  const int tid = threadIdx.x;
  if(tid<32){ redS[tid]=0.f; redQ[tid]=0.f; }
  const int node0 = blockIdx.x*16;
  const int lane = tid&63, wv = tid>>6;
  const int wm = wv&1, wn = wv>>1;
  const int mrow = lane&15, kg = (lane>>4)*8;
  for(int f=tid; f<1024; f+=256){
    float m = bn1_sum[f]*(1.f/20000.f);
    float v = bn1_sq[f]*(1.f/20000.f) - m*m;
    float a = bn1g[f]*rsqrtf(v + 1e-5f);
    int l = (f&7)*128 + (f>>3);
    s1a[l] = a; s1b[l] = bn1b[f] - m*a;
  }
  // zero halo slots: 16 nodes x {0,9} x 64 ci (persist across kc rounds)
  for(int idx=tid; idx<2048; idx+=256){
    int n = idx>>7, rem = idx&127, slot = (rem>>6)*9, ci = rem&63;
    As[n*720 + slot*72 + ci] = 0;
  }
  __syncthreads();
  f32x4 acc[4][3] = {};
  for(int kc=0; kc<2; kc++){
    if(kc) __syncthreads();              // WAR: prior mfma reads done before overwriting As/Bs
    #pragma unroll
    for(int i=0;i<4;i++){
      int idx = i*256 + tid;             // 1024 = 16 nodes x 64 cil
      int n = idx>>6, cil = idx&63;
      int ci = kc*64 + cil;
      U4 in; in.v = *(const uint4*)(rst + (size_t)(node0+n)*1024 + ci*8);
      us16* p = &As[n*720 + 72 + cil];
      #pragma unroll
      for(int t=0;t<8;t++){
        float a = s1a[t*128+ci], b = s1b[t*128+ci];
        p[t*72] = f2b(fmaf(a, b2f(in.s[t]), b));
      }
    }
    for(int s=0; s<3; s++){
      if(s) __syncthreads();             // WAR for Bs between s rounds
      #pragma unroll
      for(int i=0;i<3;i++){
        int chunk = i*256 + tid;         // 768 uint4 = 96 rows x 64 ci-half
        int brow = chunk>>3, cc = chunk&7;
        *(uint4*)&Bs[brow*72 + cc*8] =
          *(const uint4*)(Wt + s*12288 + brow*128 + kc*64 + cc*8);
      }
      __syncthreads();
      #pragma unroll
      for(int kk=0; kk<64; kk+=32){
        short8 af[4], bfr[3];
        #pragma unroll
        for(int i=0;i<4;i++){
          int r = wm*64 + i*16 + mrow;
          af[i] = *(const short8*)&As[(r>>3)*720 + ((r&7)+s)*72 + kk + kg];
        }
        #pragma unroll
        for(int j=0;j<3;j++)
          bfr[j] = *(const short8*)&Bs[(wn*48 + j*16 + mrow)*72 + kk + kg];
        #pragma unroll
        for(int i=0;i<4;i++){
          #pragma unroll
          for(int j=0;j<3;j++)
            acc[i][j] = __builtin_amdgcn_mfma_f32_16x16x32_bf16(af[i], bfr[j], acc[i][j], 0, 0, 0);
        }
      }
    }
  }
  __syncthreads();
  #pragma unroll
  for(int i=0;i<4;i++){
    #pragma unroll
    for(int j=0;j<3;j++){
      #pragma unroll
      for(int r=0;r<4;r++)
        Cs[(wm*64 + i*16 + (lane>>4)*4 + r)*100 + wn*48 + j*16 + (lane&15)] = acc[i][j][r];
    }
  }
  __syncthreads();
  const int co = tid&31, rg = tid>>5;
  const float bb1=b1[co], bb2=b2[co], bb3=b3[co];
  float s=0.f, q=0.f;
  #pragma unroll
  for(int half=0; half<2; half++){
    U4 ov;
    #pragma unroll
    for(int t=0;t<8;t++){
      int r = rg*16 + half*8 + t;
      float c1 = Cs[r*100 + co]      + bb1;
      float c2 = Cs[r*100 + co + 32] + bb2;
      float c3 = Cs[r*100 + co + 64] + bb3;
      float sg = 1.f/(1.f+__expf(-c2));
      float v = fmaf(c1, sg, c3);
      v = v>0.f ? v : 0.f;
      s += v; q += v*v;
      ov.s[t] = f2b(v);
    }
    int node = node0 + rg*2 + half;
    *(uint4*)(y2 + (size_t)node*256 + co*8) = ov.v;
  }
  atomicAdd(&redS[co], s); atomicAdd(&redQ[co], q);
  __syncthreads();
  if(tid<32)      atomicAdd(&bn2_sum[tid], redS[tid]);
  else if(tid<64) atomicAdd(&bn2_sq[tid-32], redQ[tid-32]);
}

// ---------------- final ----------------
__global__ __launch_bounds__(256) void k_final(const us16* __restrict__ y2,
    const float* __restrict__ bn2_sum, const float* __restrict__ bn2_sq,
    const float* __restrict__ bn2g, const float* __restrict__ bn2b,
    const us16* __restrict__ resid, float* __restrict__ out)
{
  __shared__ float fa[32], fb[32];
  const int tid = threadIdx.x;
  if(tid<32){
    float m = bn2_sum[tid]*(1.f/160000.f);
    float v = bn2_sq[tid]*(1.f/160000.f) - m*m;
    float a = bn2g[tid]*rsqrtf(v + 1e-5f);
    fa[tid] = a; fb[tid] = bn2b[tid] - m*a;
  }
  __syncthreads();
  size_t base = ((size_t)blockIdx.x*256 + tid)*8;
  int ch = (int)((base>>3)&31);
  float a = fa[ch], b = fb[ch];
  U4 yv, rv;
  yv.v = *(const uint4*)(y2+base);
  rv.v = *(const uint4*)(resid+base);
  float4 o0, o1;
  float vv[8];
  #pragma unroll
  for(int j=0;j<8;j++){
    float v = fmaf(a, b2f(yv.s[j]), b) + b2f(rv.s[j]);
    vv[j] = v>0.f ? v : 0.f;
  }
  o0.x=vv[0]; o0.y=vv[1]; o0.z=vv[2]; o0.w=vv[3];
  o1.x=vv[4]; o1.y=vv[5]; o1.z=vv[6]; o1.w=vv[7];
  *(float4*)(out+base)   = o0;
  *(float4*)(out+base+4) = o1;
}

extern "C" void kernel_launch(void* const* d_in, const int* in_sizes, int n_in,
                              void* d_out, int out_size, void* d_ws, size_t ws_size,
                              hipStream_t stream)
{
  const float* X    = (const float*)d_in[0];
  const int*  src   = (const int*)d_in[1];
  const int*  dst   = (const int*)d_in[2];
  const float* rp_w = (const float*)d_in[3];
  const float* rp_b = (const float*)d_in[4];
  const float* g1w1 = (const float*)d_in[5];
  const float* g1b1 = (const float*)d_in[6];
  const float* g1w2 = (const float*)d_in[7];
  const float* g1b2 = (const float*)d_in[8];
  const float* g1w3 = (const float*)d_in[9];
  const float* g1b3 = (const float*)d_in[10];
  const float* bn0g = (const float*)d_in[11];
  const float* bn0b = (const float*)d_in[12];
  const float* gatw = (const float*)d_in[13];
  const float* attnl= (const float*)d_in[14];
  const float* attnr= (const float*)d_in[15];
  const float* gbias= (const float*)d_in[16];
  const float* bn1g = (const float*)d_in[17];
  const float* bn1b = (const float*)d_in[18];
  const float* g2w1 = (const float*)d_in[19];
  const float* g2b1 = (const float*)d_in[20];
  const float* g2w2 = (const float*)d_in[21];
  const float* g2b2 = (const float*)d_in[22];
  const float* g2w3 = (const float*)d_in[23];
  const float* g2b3 = (const float*)d_in[24];
  const float* bn2g = (const float*)d_in[25];
  const float* bn2b = (const float*)d_in[26];
  float* out = (float*)d_out;
  (void)in_sizes; (void)n_in; (void)out_size; (void)ws_size;

  char* w = (char*)d_ws;
  float* bn0_sum = (float*)w;                 // 32
  float* bn0_sq  = bn0_sum + 32;              // 32
  float* bn1_sum = bn0_sum + 64;              // 1024
  float* bn1_sq  = bn1_sum + 1024;            // 1024
  float* bn2_sum = bn1_sq  + 1024;            // 32
  float* bn2_sq  = bn2_sum + 32;              // 32
  float* wl      = bn2_sq + 32;               // 1024 (zeroed: accumulated atomically)
  float* wr      = wl + 1024;                 // 1024
  int*   counts  = (int*)(wr + 1024);         // 20000
  size_t zeroBytes = (size_t)((char*)(counts + NN) - w);   // ~96.9 KB
  int*   offsets = counts + NN;               // 20004
  int*   cursor  = offsets + 20004;           // 20000
  int*   esrc    = cursor + NN;               // 320000
  float* el      = (float*)(esrc + NE);       // 80000
  float* er      = el + NN*4;                 // 80000
  float* ew      = er + NN*4;                 // 1,280,000
  us16*  wb      = (us16*)(ew + (size_t)NE*4);// 262144
  us16*  resid   = wb + 262144;               // 5,120,000
  us16*  gc1     = resid + 5120000;           // 5,120,000 (raw gated conv1)
  us16*  Axg     = gc1   + 5120000;           // 20,480,000  [hd][node][256]
  us16*  rst     = Axg   + 20480000;          // 20,480,000
  us16*  Wt      = rst   + 20480000;          // 36,864
  us16*  Wt1     = Wt    + 36864;             // 12,288
  us16*  y2      = gc1;                       // alias: gc1 dead after k_agg2

  hipMemsetAsync(d_ws, 0, zeroBytes, stream);
  k_misc<<<1730, 256, 0, stream>>>(gatw, wb, g2w1, g2w2, g2w3, Wt,
                                   g1w1, g1w2, g1w3, rp_w, Wt1,
                                   attnl, attnr, wl, wr, dst, counts);
  k_gemm1<<<1251, 256, 0, stream>>>(X, Wt1, g1b1, g1b2, g1b3, rp_b,
                                    gc1, resid, bn0_sum, bn0_sq,
                                    counts, offsets, cursor);
  k_eler2<<<5000, 256, 0, stream>>>(gc1, bn0_sum, bn0_sq, bn0g, bn0b, wl, wr, el, er);
  k_scatter<<<1250, 256, 0, stream>>>(src, dst, cursor, esrc, el, er, ew);
  k_agg2<<<5000, 256, 0, stream>>>(offsets, esrc, ew, gc1, bn0_sum, bn0_sq, bn0g, bn0b, Axg);
  k_gemm3<<<dim3(157, 2, 4), 256, 0, stream>>>(Axg, wb, gbias, rst, bn1_sum, bn1_sq);
  k_gemm2<<<1250, 256, 0, stream>>>(rst, Wt, bn1_sum, bn1_sq, bn1g, bn1b,
                                    g2b1, g2b2, g2b3, y2, bn2_sum, bn2_sq);
  k_final<<<2500, 256, 0, stream>>>(y2, bn2_sum, bn2_sq, bn2g, bn2b, resid, out);
}